// Round 13
// baseline (28.963 us; speedup 1.0000x reference)
//
#include <hip/hip_runtime.h>

#define NN 2048
#define HALF 16777216ull              // B*N*N = 4*2048*2048
#define MLPB 256                      // MLP blocks, 32 rows each; idx blocks follow

typedef float  __attribute__((ext_vector_type(4))) f32x4;
typedef short  __attribute__((ext_vector_type(8))) s16x8;
typedef ushort __attribute__((ext_vector_type(4))) u16x4;

// fp32 -> bf16 (RTNE) — same bit-exact helper as all passing rounds
__device__ __forceinline__ ushort f2bf(float f) {
    union { float f; uint32_t u; } v; v.f = f;
    const uint32_t r = v.u + 0x7FFFu + ((v.u >> 16) & 1u);
    return (ushort)(r >> 16);
}

// Gather one MFMA A-fragment of W^T directly from fp32 W[k][n] (ldn = 256).
__device__ __forceinline__ s16x8 gatherW(const float* __restrict__ W, int ng, int k0) {
    s16x8 a;
    #pragma unroll
    for (int j = 0; j < 8; ++j)
        a[j] = (short)f2bf(W[(k0 + j) * 256 + ng]);
    return a;
}

// ---------------- single kernel: {MFMA MLP + icut adj} | {idx fill} ----------------
// blocks [0,256):     32 rows each: shift (LDS), then adj[row][j] = sigmoid(s-7j);
//                     only the first 256-col chunk needs exp (z < -20 beyond it).
// blocks [256,2304):  out[HALF + row*NN + j] = (float)j  (4 rows each)
// LDS union: xs (32x136 bf16, layer-1 input) and h1 (32x264 bf16, layer-2 input)
// share one buffer — live ranges are disjoint (extra barrier separates them).
__global__ __launch_bounds__(256) void dgg_all(
    const float* __restrict__ x,
    const float* __restrict__ Wmu1, const float* __restrict__ bmu1,
    const float* __restrict__ Wmu2, const float* __restrict__ bmu2,
    const float* __restrict__ Wkp,  const float* __restrict__ bkp,
    float* __restrict__ out)
{
    __shared__ ushort smem[32 * 264];   // 16,896 B: xs(stride 136) then h1(stride 264)
    __shared__ float  red[4][2][16];
    __shared__ float  sh_shift[32];

    const int bid = blockIdx.x, t = threadIdx.x;
    const int lane = t & 63, w = t >> 6;

    if (bid >= MLPB) {
        // ---- idx fill: pure streaming stores ----
        const int row = (bid - MLPB) * 4 + w;
        float* idx = out + HALF + (size_t)row * NN;
        #pragma unroll
        for (int i = 0; i < 8; ++i) {
            const int c = i * 256 + lane * 4;
            f32x4 v = {(float)c, (float)(c + 1), (float)(c + 2), (float)(c + 3)};
            *(f32x4*)(idx + c) = v;
        }
        return;
    }

    // ---- MFMA MLP path (math identical to round 12) ----
    const int l16 = lane & 15, lq = lane >> 4;
    const int row0 = bid * 32;
    const int k0l = lq * 8;           // this lane's k-offset within a 32-chunk

    // stage x (32 rows x 128 fp32) -> bf16 LDS row-major (stride 136)
    {
        const int r = t >> 3, k0 = (t & 7) * 16;
        const float* src = x + (size_t)(row0 + r) * 128 + k0;
        s16x8 s0, s1;
        #pragma unroll
        for (int q = 0; q < 8; ++q) {
            s0[q] = (short)f2bf(src[q]);
            s1[q] = (short)f2bf(src[8 + q]);
        }
        *(s16x8*)&smem[r * 136 + k0]     = s0;
        *(s16x8*)&smem[r * 136 + k0 + 8] = s1;
    }
    __syncthreads();

    // layer 1: K=128 (4 chunks of 32), reads xs region of smem
    f32x4 acc[2][4] = {};
    #pragma unroll
    for (int kc = 0; kc < 4; ++kc) {
        const s16x8 b0 = *(const s16x8*)&smem[l16 * 136 + kc * 32 + k0l];
        const s16x8 b1 = *(const s16x8*)&smem[(16 + l16) * 136 + kc * 32 + k0l];
        #pragma unroll
        for (int nt = 0; nt < 4; ++nt) {
            const int ng = (w * 4 + nt) * 16 + l16;
            const s16x8 a = gatherW(Wmu1, ng, kc * 32 + k0l);
            acc[0][nt] = __builtin_amdgcn_mfma_f32_16x16x32_bf16(a, b0, acc[0][nt], 0, 0, 0);
            acc[1][nt] = __builtin_amdgcn_mfma_f32_16x16x32_bf16(a, b1, acc[1][nt], 0, 0, 0);
        }
    }
    __syncthreads();                  // all xs reads done before h1 overwrites smem

    // bias + relu -> h1 bf16 row-major (stride 264), same smem buffer
    #pragma unroll
    for (int nt = 0; nt < 4; ++nt) {
        const int c0 = (w * 4 + nt) * 16 + lq * 4;
        const f32x4 bv = *(const f32x4*)&bmu1[c0];
        #pragma unroll
        for (int mt = 0; mt < 2; ++mt) {
            u16x4 hv;
            #pragma unroll
            for (int reg = 0; reg < 4; ++reg)
                hv[reg] = f2bf(fmaxf(acc[mt][nt][reg] + bv[reg], 0.f));
            *(u16x4*)&smem[(mt * 16 + l16) * 264 + c0] = hv;
        }
    }
    __syncthreads();

    // layer 2: K=256 (8 chunks of 32), reads h1 region of smem
    f32x4 acc2[2][4] = {};
    #pragma unroll
    for (int kc = 0; kc < 8; ++kc) {
        const s16x8 b0 = *(const s16x8*)&smem[l16 * 264 + kc * 32 + k0l];
        const s16x8 b1 = *(const s16x8*)&smem[(16 + l16) * 264 + kc * 32 + k0l];
        #pragma unroll
        for (int nt = 0; nt < 4; ++nt) {
            const int ng = (w * 4 + nt) * 16 + l16;
            const s16x8 a = gatherW(Wmu2, ng, kc * 32 + k0l);
            acc2[0][nt] = __builtin_amdgcn_mfma_f32_16x16x32_bf16(a, b0, acc2[0][nt], 0, 0, 0);
            acc2[1][nt] = __builtin_amdgcn_mfma_f32_16x16x32_bf16(a, b1, acc2[1][nt], 0, 0, 0);
        }
    }

    // (h2 + b2) . wkp, reduce within wave, then across waves
    float p0 = 0.f, p1 = 0.f;
    #pragma unroll
    for (int nt = 0; nt < 4; ++nt) {
        const int c0 = (w * 4 + nt) * 16 + lq * 4;
        const f32x4 b2 = *(const f32x4*)&bmu2[c0];
        const f32x4 wk = *(const f32x4*)&Wkp[c0];
        #pragma unroll
        for (int reg = 0; reg < 4; ++reg) {
            p0 = fmaf(acc2[0][nt][reg] + b2[reg], wk[reg], p0);
            p1 = fmaf(acc2[1][nt][reg] + b2[reg], wk[reg], p1);
        }
    }
    p0 += __shfl_xor(p0, 16, 64);  p0 += __shfl_xor(p0, 32, 64);
    p1 += __shfl_xor(p1, 16, 64);  p1 += __shfl_xor(p1, 32, 64);
    if (lane < 16) { red[w][0][lane] = p0; red[w][1][lane] = p1; }
    __syncthreads();

    if (t < 32) {
        const int mt = t >> 4, m = t & 15;
        const float s = red[0][mt][m] + red[1][mt][m] + red[2][mt][m] + red[3][mt][m];
        sh_shift[t] = 7.0f * (s + bkp[0]) + 2.0f;   // fold the +2 here
    }
    __syncthreads();

    // ---- adj fill: wave w owns rows w*8..w*8+7; exp only below icut ----
    #pragma unroll 2
    for (int rr = 0; rr < 8; ++rr) {
        const int r = w * 8 + rr;
        const float s = sh_shift[r];
        // exp needed only while s - 1792*i > -20  =>  i < (s+20)/1792
        const int icut = min(8, max(0, (int)ceilf((s + 20.0f) * (1.0f / 1792.0f))));
        float* adj = out + (size_t)(row0 + r) * NN;
        for (int i = 0; i < 8; ++i) {
            const int c = i * 256 + lane * 4;
            f32x4 a = {0.f, 0.f, 0.f, 0.f};
            if (i < icut) {                          // wave-uniform branch
                #pragma unroll
                for (int q = 0; q < 4; ++q) {
                    const float z = fmaf(-7.0f, (float)(c + q), s);
                    a[q] = 1.0f / (1.0f + __expf(-z));
                }
            }
            *(f32x4*)(adj + c) = a;
        }
    }
}

extern "C" void kernel_launch(void* const* d_in, const int* in_sizes, int n_in,
                              void* d_out, int out_size, void* d_ws, size_t ws_size,
                              hipStream_t stream)
{
    (void)in_sizes; (void)n_in; (void)out_size; (void)d_ws; (void)ws_size;
    const float* x    = (const float*)d_in[0];
    // d_in[1..5] dead: softmax over size-1 axis == 1 -> edge_prob == 1/N exactly;
    // stable argsort of all-ties rows == identity permutation.
    const float* Wmu1 = (const float*)d_in[6];
    const float* bmu1 = (const float*)d_in[7];
    const float* Wmu2 = (const float*)d_in[8];
    const float* bmu2 = (const float*)d_in[9];
    const float* Wkp  = (const float*)d_in[10];
    const float* bkp  = (const float*)d_in[11];

    hipLaunchKernelGGL(dgg_all, dim3(MLPB + 2048), dim3(256), 0, stream,
                       x, Wmu1, bmu1, Wmu2, bmu2, Wkp, bkp, (float*)d_out);
}